// Round 6
// baseline (133.368 us; speedup 1.0000x reference)
//
#include <hip/hip_runtime.h>

#define B_ROWS   8192
#define BMASK    8191
#define DIM      128
#define CTILE    64          // columns per tile
#define CHUNK0   20          // z0 col-tiles per block
#define CHUNK1   16          // z1 col-tiles per block
#define NZ1      512         // z1 blocks = 64 panels * (128/CHUNK1)
#define BLK64    16384       // bytes per packed 64-row block (64*128*2)

typedef __attribute__((ext_vector_type(8)))  __bf16 bf16x8;
typedef __attribute__((ext_vector_type(2)))  __bf16 bf16x2;
typedef __attribute__((ext_vector_type(16))) float  f32x16;

// sqrt(log2(e)/0.07) folded symmetrically into both row normalizations.
#define RBSCALE 4.5398159f

__device__ __forceinline__ float fast_exp2(float x) {
#if __has_builtin(__builtin_amdgcn_exp2f)
    return __builtin_amdgcn_exp2f(x);
#else
    return exp2f(x);
#endif
}

// One wave per row: norm -> scale -> bf16 -> k-major packed layout
// packed[row>>6][granule=k/8][row&63][8 bf16]. Block 0 zeroes accumulators.
__global__ __launch_bounds__(256)
void prep_kernel(const float* __restrict__ e1, const float* __restrict__ e2,
                 char* __restrict__ p1, char* __restrict__ p2,
                 float* __restrict__ acc) {
    if (blockIdx.x == 0 && threadIdx.x < 4) acc[threadIdx.x] = 0.f;
    int gw   = (blockIdx.x * 256 + threadIdx.x) >> 6;   // 0..16383
    int lane = threadIdx.x & 63;
    const float* src; char* dst; int row;
    if (gw < B_ROWS) { src = e1; dst = p1; row = gw; }
    else             { src = e2; dst = p2; row = gw - B_ROWS; }
    float2 v = ((const float2*)(src + (size_t)row * DIM))[lane];
    float ss = v.x * v.x + v.y * v.y;
#pragma unroll
    for (int o = 32; o > 0; o >>= 1) ss += __shfl_xor(ss, o);   // butterfly: all lanes get total
    float rb = RBSCALE / sqrtf(ss);
    bf16x2 pk = { (__bf16)(v.x * rb), (__bf16)(v.y * rb) };
    size_t off = (size_t)(row >> 6) * BLK64 + (size_t)(lane >> 2) * 1024
               + (size_t)(row & 63) * 16 + (size_t)(lane & 3) * 4;
    *(bf16x2*)(dst + off) = pk;
}

// Epilogue for one 64x32 accumulator pair: exp2 + (optional) mask + sum.
// 4-way partial sums break the serial dependent-add chain.
template <bool MASKED>
__device__ __forceinline__ float tile_sum(const f32x16& a0, const f32x16& a1,
                                          int i00, int c) {
    float s0 = 0.f, s1 = 0.f, s2 = 0.f, s3 = 0.f;
#pragma unroll
    for (int g = 0; g < 2; ++g) {
        const f32x16& a = g ? a1 : a0;
        int ib = i00 + g * 32;
#pragma unroll
        for (int r = 0; r < 16; ++r) {
            float ev = fast_exp2(a[r]);
            float add;
            if (MASKED) {
                int i = ib + (r & 3) + 8 * (r >> 2);   // m74/m101 C/D row map
                int d = (c - i) & BMASK;               // (c-i) mod B
                add = (d > i) ? ev : 0.f;
            } else {
                add = ev;
            }
            if      ((r & 3) == 0) s0 += add;
            else if ((r & 3) == 1) s1 += add;
            else if ((r & 3) == 2) s2 += add;
            else                   s3 += add;
        }
    }
    return (s0 + s1) + (s2 + s3);
}

// B-fragment load into NAMED registers (no array, no address-taken -> no scratch).
#define LOADB(kk) do {                                                          \
    const char* gp_ = Bpack + (size_t)(tile_c0(kk) >> 6) * BLK64 + lane_off;    \
    b0 = *(const bf16x8*)(gp_ +     0);                                          \
    b1 = *(const bf16x8*)(gp_ +  2048);                                          \
    b2 = *(const bf16x8*)(gp_ +  4096);                                          \
    b3 = *(const bf16x8*)(gp_ +  6144);                                          \
    b4 = *(const bf16x8*)(gp_ +  8192);                                          \
    b5 = *(const bf16x8*)(gp_ + 10240);                                          \
    b6 = *(const bf16x8*)(gp_ + 12288);                                          \
    b7 = *(const bf16x8*)(gp_ + 14336);                                          \
} while (0)

// LDS-free streaming: 128-row A panel in registers; per tile each wave pulls its
// 8 KB B-fragment straight from L2 into NAMED registers.
// No barriers in the main loop. KEY CHANGE vs r5: 3 blocks/CU (launch_bounds
// (256,3), ~160 regs/wave) -> 3 waves/SIMD from DIFFERENT blocks at different
// phases, so MFMA / exp-epilogue / load-wait phases overlap across waves
// instead of running in 2-wave lockstep (which serialized phase sums at 45 us).
// 756 blocks (512 z1 @16 tiles + 244 z0 @<=20 tiles) -> one dispatch round,
// typical CU = 2x16 + 1x20 = 52 tiles vs 48.7 mean.
__global__ __launch_bounds__(256, 3)
void pair_kernel(const char* __restrict__ P1, const char* __restrict__ P2,
                 float* __restrict__ accg, float* __restrict__ out,
                 int nblocks) {
    __shared__ float red[4];

    const int tid = threadIdx.x;
    const int b   = blockIdx.x;

    // ---- block -> (z, panel p, tile chunk [k0,k1)) ----  (z1 blocks first)
    int z, p, k0, k1;
    if (b < NZ1) {
        z = 1; p = b >> 3; k0 = (b & 7) * CHUNK1; k1 = k0 + CHUNK1;
    } else {
        z = 0;
        int bb0 = b - NZ1, accb = 0;
        p = 0;
        for (;; ++p) {
            int i0t = 128 * p;
            int e1t = (i0t > 128) ? i0t : 128;
            int cnt = 2 + (B_ROWS - e1t) / 64;
            int nb  = (cnt + CHUNK0 - 1) / CHUNK0;
            if (bb0 < accb + nb) {
                int s = bb0 - accb;
                k0 = s * CHUNK0;
                k1 = (k0 + CHUNK0 < cnt) ? (k0 + CHUNK0) : cnt;
                break;
            }
            accb += nb;
        }
    }
    const int i0 = 128 * p;
    const int e1 = (i0 > 128) ? i0 : 128;

    const char* Bpack = (z == 0) ? P1 : P2;

    // tile index k -> column origin c0; masked flag (z=0 only)
    auto tile_c0 = [&](int k) -> int {
        if (z) return k * CTILE;
        int e = (k == 0) ? 64 : e1 + (k - 1) * 64;
        return (i0 + e) & BMASK;
    };
    auto tile_masked = [&](int k) -> bool {
        if (z) return false;
        int e = (k == 0) ? 64 : e1 + (k - 1) * 64;
        return (e < i0 + 256) || (e > 8128);
    };

    const int w  = tid >> 6, lane = tid & 63;
    const int w2 = w >> 1, wc = w & 1;
    const int l  = lane & 31, h = lane >> 5;

    // ---- A panel -> registers: rows i0 + w2*64 + [0,64), k-major packed ----
    bf16x8 af[2][8];
    {
        const char* ap = P1 + (size_t)(p * 2 + w2) * BLK64;
#pragma unroll
        for (int g = 0; g < 2; ++g)
#pragma unroll
            for (int s = 0; s < 8; ++s)
                af[g][s] = *(const bf16x8*)(ap + (size_t)(s * 2 + h) * 1024
                                               + (size_t)(g * 32 + l) * 16);
    }

    const int i00 = i0 + w2 * 64 + 4 * h;   // epilogue row base for this lane
    const int cb  = wc * 32 + l;            // col offset within tile
    const size_t lane_off = (size_t)cb * 16 + (size_t)h * 1024;

    float sacc = 0.f;
    bf16x8 b0, b1, b2, b3, b4, b5, b6, b7;
    LOADB(k0);

    for (int k = k0; k < k1; ++k) {
        f32x16 r0, r1;
#pragma unroll
        for (int r = 0; r < 16; ++r) { r0[r] = 0.f; r1[r] = 0.f; }

        r0 = __builtin_amdgcn_mfma_f32_32x32x16_bf16(af[0][0], b0, r0, 0, 0, 0);
        r1 = __builtin_amdgcn_mfma_f32_32x32x16_bf16(af[1][0], b0, r1, 0, 0, 0);
        r0 = __builtin_amdgcn_mfma_f32_32x32x16_bf16(af[0][1], b1, r0, 0, 0, 0);
        r1 = __builtin_amdgcn_mfma_f32_32x32x16_bf16(af[1][1], b1, r1, 0, 0, 0);
        r0 = __builtin_amdgcn_mfma_f32_32x32x16_bf16(af[0][2], b2, r0, 0, 0, 0);
        r1 = __builtin_amdgcn_mfma_f32_32x32x16_bf16(af[1][2], b2, r1, 0, 0, 0);
        r0 = __builtin_amdgcn_mfma_f32_32x32x16_bf16(af[0][3], b3, r0, 0, 0, 0);
        r1 = __builtin_amdgcn_mfma_f32_32x32x16_bf16(af[1][3], b3, r1, 0, 0, 0);
        r0 = __builtin_amdgcn_mfma_f32_32x32x16_bf16(af[0][4], b4, r0, 0, 0, 0);
        r1 = __builtin_amdgcn_mfma_f32_32x32x16_bf16(af[1][4], b4, r1, 0, 0, 0);
        r0 = __builtin_amdgcn_mfma_f32_32x32x16_bf16(af[0][5], b5, r0, 0, 0, 0);
        r1 = __builtin_amdgcn_mfma_f32_32x32x16_bf16(af[1][5], b5, r1, 0, 0, 0);
        r0 = __builtin_amdgcn_mfma_f32_32x32x16_bf16(af[0][6], b6, r0, 0, 0, 0);
        r1 = __builtin_amdgcn_mfma_f32_32x32x16_bf16(af[1][6], b6, r1, 0, 0, 0);
        r0 = __builtin_amdgcn_mfma_f32_32x32x16_bf16(af[0][7], b7, r0, 0, 0, 0);
        r1 = __builtin_amdgcn_mfma_f32_32x32x16_bf16(af[1][7], b7, r1, 0, 0, 0);

        int  c = tile_c0(k) + cb;
        bool m = tile_masked(k);

        // issue next tile's loads now (regs free: MFMAs consumed them);
        // pin them before the epilogue so its VALU hides the L2 latency
        if (k + 1 < k1) LOADB(k + 1);
        __builtin_amdgcn_sched_barrier(0);

        sacc += m ? tile_sum<true >(r0, r1, i00, c)
                  : tile_sum<false>(r0, r1, i00, c);
    }

#pragma unroll
    for (int o = 32; o > 0; o >>= 1) sacc += __shfl_down(sacc, o);
    if (lane == 0) red[w] = sacc;
    __syncthreads();
    if (tid == 0) {
        atomicAdd(&accg[z], red[0] + red[1] + red[2] + red[3]);
        __threadfence();
        unsigned prev = atomicAdd((unsigned*)&accg[2], 1u);
        if (prev == (unsigned)(nblocks - 1)) {
            float l1 = atomicAdd(&accg[0], 0.f);
            float l2 = atomicAdd(&accg[1], 0.f);
            out[0] = -logf(l1 / l2);
        }
    }
}

extern "C" void kernel_launch(void* const* d_in, const int* in_sizes, int n_in,
                              void* d_out, int out_size, void* d_ws, size_t ws_size,
                              hipStream_t stream) {
    (void)in_sizes; (void)n_in; (void)out_size; (void)ws_size;
    const float* e1 = (const float*)d_in[0];
    const float* e2 = (const float*)d_in[1];
    float* out = (float*)d_out;
    char*  ws  = (char*)d_ws;

    float* acc = (float*)ws;                       // 16 B: l1, l2, counter, pad
    char*  p1  = ws + 4096;                        // 2 MB packed E1
    char*  p2  = ws + 4096 + 2097152;              // 2 MB packed E2

    // z0 block count (must match device-side mapping; z1 blocks come first)
    int nz0 = 0;
    for (int p = 0; p < 64; ++p) {
        int i0 = 128 * p;
        int e1t = (i0 > 128) ? i0 : 128;
        int cnt = 2 + (B_ROWS - e1t) / 64;
        nz0 += (cnt + CHUNK0 - 1) / CHUNK0;
    }
    int nblocks = NZ1 + nz0;   // 512 + 244 = 756 <= 768 (3 blocks/CU) -> one round

    prep_kernel<<<dim3(4096), dim3(256), 0, stream>>>(e1, e2, p1, p2, acc);
    pair_kernel<<<dim3(nblocks), dim3(256), 0, stream>>>(p1, p2, acc, out, nblocks);
}

// Round 7
// 106.966 us; speedup vs baseline: 1.2468x; 1.2468x over previous
//
#include <hip/hip_runtime.h>

#define B_ROWS   8192
#define BMASK    8191
#define DIM      128
#define CTILE    64          // columns per tile
#define CHUNK0   20          // z0 col-tiles per block
#define CHUNK1   32          // z1 col-tiles per block
#define NZ1      256         // z1 blocks = 64 panels * (128/CHUNK1)
#define BLK64    16384       // bytes per packed 64-row block (64*128*2)

typedef __attribute__((ext_vector_type(8)))  __bf16 bf16x8;
typedef __attribute__((ext_vector_type(2)))  __bf16 bf16x2;
typedef __attribute__((ext_vector_type(16))) float  f32x16;

// sqrt(log2(e)/0.07) folded symmetrically into both row normalizations.
#define RBSCALE 4.5398159f

__device__ __forceinline__ float fast_exp2(float x) {
#if __has_builtin(__builtin_amdgcn_exp2f)
    return __builtin_amdgcn_exp2f(x);
#else
    return exp2f(x);
#endif
}

// One wave per row: norm -> scale -> bf16 -> k-major packed layout
// packed[row>>6][granule=k/8][row&63][8 bf16]. Block 0 zeroes accumulators.
__global__ __launch_bounds__(256)
void prep_kernel(const float* __restrict__ e1, const float* __restrict__ e2,
                 char* __restrict__ p1, char* __restrict__ p2,
                 float* __restrict__ acc) {
    if (blockIdx.x == 0 && threadIdx.x < 4) acc[threadIdx.x] = 0.f;
    int gw   = (blockIdx.x * 256 + threadIdx.x) >> 6;   // 0..16383
    int lane = threadIdx.x & 63;
    const float* src; char* dst; int row;
    if (gw < B_ROWS) { src = e1; dst = p1; row = gw; }
    else             { src = e2; dst = p2; row = gw - B_ROWS; }
    float2 v = ((const float2*)(src + (size_t)row * DIM))[lane];
    float ss = v.x * v.x + v.y * v.y;
#pragma unroll
    for (int o = 32; o > 0; o >>= 1) ss += __shfl_xor(ss, o);   // butterfly: all lanes get total
    float rb = RBSCALE / sqrtf(ss);
    bf16x2 pk = { (__bf16)(v.x * rb), (__bf16)(v.y * rb) };
    size_t off = (size_t)(row >> 6) * BLK64 + (size_t)(lane >> 2) * 1024
               + (size_t)(row & 63) * 16 + (size_t)(lane & 3) * 4;
    *(bf16x2*)(dst + off) = pk;
}

// Standalone epilogue (pipeline tails): exp2 + (optional) mask + sum.
template <bool MASKED>
__device__ __forceinline__ float tile_sum(const f32x16& a0, const f32x16& a1,
                                          int i00, int c) {
    float s0 = 0.f, s1 = 0.f, s2 = 0.f, s3 = 0.f;
#pragma unroll
    for (int g = 0; g < 2; ++g) {
        const f32x16& a = g ? a1 : a0;
        int ib = i00 + g * 32;
#pragma unroll
        for (int r = 0; r < 16; ++r) {
            float ev = fast_exp2(a[r]);
            float add;
            if (MASKED) {
                int i = ib + (r & 3) + 8 * (r >> 2);   // m74/m101 C/D row map
                int d = (c - i) & BMASK;               // (c-i) mod B
                add = (d > i) ? ev : 0.f;
            } else {
                add = ev;
            }
            if      ((r & 3) == 0) s0 += add;
            else if ((r & 3) == 1) s1 += add;
            else if ((r & 3) == 2) s2 += add;
            else                   s3 += add;
        }
    }
    return (s0 + s1) + (s2 + s3);
}

#define MFMA32 __builtin_amdgcn_mfma_f32_32x32x16_bf16
#define SBAR0  __builtin_amdgcn_sched_barrier(0)

// Load a 8 KB B-fragment into NAMED register set P (E or O). No arrays.
#define LOADB(P, ADDR) do { const char* gp_ = (ADDR);            \
    b##P##0 = *(const bf16x8*)(gp_ +     0);                      \
    b##P##1 = *(const bf16x8*)(gp_ +  2048);                      \
    b##P##2 = *(const bf16x8*)(gp_ +  4096);                      \
    b##P##3 = *(const bf16x8*)(gp_ +  6144);                      \
    b##P##4 = *(const bf16x8*)(gp_ +  8192);                      \
    b##P##5 = *(const bf16x8*)(gp_ + 10240);                      \
    b##P##6 = *(const bf16x8*)(gp_ + 12288);                      \
    b##P##7 = *(const bf16x8*)(gp_ + 14336);                      \
} while (0)

// One interleave group: 2 MFMAs of the CURRENT tile + 4 epilogue elems of the
// PREVIOUS tile. sched_barrier(0) pins the interleave so epilogue VALU issues
// into the matrix-pipe occupancy gaps (intra-wave MFMA/VALU overlap).
#define GRP_NM(S, BREG, RC0, RC1, RP, RB)                         \
    RC0 = MFMA32(af[0][S], BREG, RC0, 0, 0, 0);                   \
    RC1 = MFMA32(af[1][S], BREG, RC1, 0, 0, 0);                   \
    { float e0_ = fast_exp2((RP)[(RB)+0]);                        \
      float e1_ = fast_exp2((RP)[(RB)+1]);                        \
      float e2_ = fast_exp2((RP)[(RB)+2]);                        \
      float e3_ = fast_exp2((RP)[(RB)+3]);                        \
      s0 += e0_; s1 += e1_; s2 += e2_; s3 += e3_; }               \
    SBAR0;

// Masked variant: mask (d > i) is universally correct for z0 (unmasked tiles
// are just the always-true case), so it is applied unconditionally.
#define GRP_M(S, BREG, RC0, RC1, RP, RB, IB, CP)                  \
    RC0 = MFMA32(af[0][S], BREG, RC0, 0, 0, 0);                   \
    RC1 = MFMA32(af[1][S], BREG, RC1, 0, 0, 0);                   \
    { int i_ = (IB) + 2*(RB);                                     \
      float e0_ = fast_exp2((RP)[(RB)+0]);                        \
      float e1_ = fast_exp2((RP)[(RB)+1]);                        \
      float e2_ = fast_exp2((RP)[(RB)+2]);                        \
      float e3_ = fast_exp2((RP)[(RB)+3]);                        \
      int d0_ = ((CP) - i_    ) & BMASK;                          \
      int d1_ = ((CP) - i_ - 1) & BMASK;                          \
      int d2_ = ((CP) - i_ - 2) & BMASK;                          \
      int d3_ = ((CP) - i_ - 3) & BMASK;                          \
      s0 += (d0_ > i_    ) ? e0_ : 0.f;                           \
      s1 += (d1_ > i_ + 1) ? e1_ : 0.f;                           \
      s2 += (d2_ > i_ + 2) ? e2_ : 0.f;                           \
      s3 += (d3_ > i_ + 3) ? e3_ : 0.f; }                         \
    SBAR0;

#define ZERO_ACC(RC0, RC1)                                        \
    _Pragma("unroll")                                             \
    for (int r_ = 0; r_ < 16; ++r_) { RC0[r_] = 0.f; RC1[r_] = 0.f; }

// Pipeline body: compute acc(RC) from buffer BP, interleaving epilogue of prev
// acc (RP0/RP1); then prefetch 2 tiles ahead into the just-consumed buffer.
#define BODY_NM(BP, RC0, RC1, RP0, RP1, PREF)                     \
  { ZERO_ACC(RC0, RC1)                                            \
    GRP_NM(0, b##BP##0, RC0, RC1, RP0, 0)                         \
    GRP_NM(1, b##BP##1, RC0, RC1, RP0, 4)                         \
    GRP_NM(2, b##BP##2, RC0, RC1, RP0, 8)                         \
    GRP_NM(3, b##BP##3, RC0, RC1, RP0, 12)                        \
    GRP_NM(4, b##BP##4, RC0, RC1, RP1, 0)                         \
    GRP_NM(5, b##BP##5, RC0, RC1, RP1, 4)                         \
    GRP_NM(6, b##BP##6, RC0, RC1, RP1, 8)                         \
    GRP_NM(7, b##BP##7, RC0, RC1, RP1, 12)                        \
    PREF; }

#define BODY_M(BP, RC0, RC1, RP0, RP1, CP, PREF)                  \
  { ZERO_ACC(RC0, RC1)                                            \
    GRP_M(0, b##BP##0, RC0, RC1, RP0, 0,  i00,      CP)           \
    GRP_M(1, b##BP##1, RC0, RC1, RP0, 4,  i00,      CP)           \
    GRP_M(2, b##BP##2, RC0, RC1, RP0, 8,  i00,      CP)           \
    GRP_M(3, b##BP##3, RC0, RC1, RP0, 12, i00,      CP)           \
    GRP_M(4, b##BP##4, RC0, RC1, RP1, 0,  i00 + 32, CP)           \
    GRP_M(5, b##BP##5, RC0, RC1, RP1, 4,  i00 + 32, CP)           \
    GRP_M(6, b##BP##6, RC0, RC1, RP1, 8,  i00 + 32, CP)           \
    GRP_M(7, b##BP##7, RC0, RC1, RP1, 12, i00 + 32, CP)           \
    PREF; }

// Prologue body: no previous epilogue to interleave.
#define BODY0(BP, RC0, RC1, PREF)                                 \
  { ZERO_ACC(RC0, RC1)                                            \
    RC0 = MFMA32(af[0][0], b##BP##0, RC0,0,0,0); RC1 = MFMA32(af[1][0], b##BP##0, RC1,0,0,0); \
    RC0 = MFMA32(af[0][1], b##BP##1, RC0,0,0,0); RC1 = MFMA32(af[1][1], b##BP##1, RC1,0,0,0); \
    RC0 = MFMA32(af[0][2], b##BP##2, RC0,0,0,0); RC1 = MFMA32(af[1][2], b##BP##2, RC1,0,0,0); \
    RC0 = MFMA32(af[0][3], b##BP##3, RC0,0,0,0); RC1 = MFMA32(af[1][3], b##BP##3, RC1,0,0,0); \
    RC0 = MFMA32(af[0][4], b##BP##4, RC0,0,0,0); RC1 = MFMA32(af[1][4], b##BP##4, RC1,0,0,0); \
    RC0 = MFMA32(af[0][5], b##BP##5, RC0,0,0,0); RC1 = MFMA32(af[1][5], b##BP##5, RC1,0,0,0); \
    RC0 = MFMA32(af[0][6], b##BP##6, RC0,0,0,0); RC1 = MFMA32(af[1][6], b##BP##6, RC1,0,0,0); \
    RC0 = MFMA32(af[0][7], b##BP##7, RC0,0,0,0); RC1 = MFMA32(af[1][7], b##BP##7, RC1,0,0,0); \
    PREF; }

// LDS-free streaming GEMM+exp-reduce. vs r5: (1) prefetch distance 2 via two
// named B-register sets (full-iteration latency cover), (2) epilogue of tile
// k-1 interleaved into tile k's MFMA chain (intra-wave pipe overlap, immune
// to 2-wave lockstep), (3) z-specialized loops (z1 maskless; z0 always-mask).
// ~210 VGPR < 256 cap at 2 blocks/CU; 500 blocks -> single dispatch round.
__global__ __launch_bounds__(256, 2)
void pair_kernel(const char* __restrict__ P1, const char* __restrict__ P2,
                 float* __restrict__ accg, float* __restrict__ out,
                 int nblocks) {
    __shared__ float red[4];

    const int tid = threadIdx.x;
    const int b   = blockIdx.x;

    // ---- block -> (z, panel p, tile chunk [k0,k1)) ----  (z1 blocks first)
    int z, p, k0, k1;
    if (b < NZ1) {
        z = 1; p = b >> 2; k0 = (b & 3) * CHUNK1; k1 = k0 + CHUNK1;
    } else {
        z = 0;
        int bb0 = b - NZ1, accb = 0;
        p = 0;
        for (;; ++p) {
            int i0t = 128 * p;
            int e1t = (i0t > 128) ? i0t : 128;
            int cnt = 2 + (B_ROWS - e1t) / 64;
            int nb  = (cnt + CHUNK0 - 1) / CHUNK0;
            if (bb0 < accb + nb) {
                int s = bb0 - accb;
                k0 = s * CHUNK0;
                k1 = (k0 + CHUNK0 < cnt) ? (k0 + CHUNK0) : cnt;
                break;
            }
            accb += nb;
        }
    }
    const int i0 = 128 * p;
    const int e1 = (i0 > 128) ? i0 : 128;

    const char* Bpack = (z == 0) ? P1 : P2;

    const int w  = tid >> 6, lane = tid & 63;
    const int w2 = w >> 1, wc = w & 1;
    const int l  = lane & 31, h = lane >> 5;

    // ---- A panel -> registers: rows i0 + w2*64 + [0,64), k-major packed ----
    bf16x8 af[2][8];
    {
        const char* ap = P1 + (size_t)(p * 2 + w2) * BLK64;
#pragma unroll
        for (int g = 0; g < 2; ++g)
#pragma unroll
            for (int s = 0; s < 8; ++s)
                af[g][s] = *(const bf16x8*)(ap + (size_t)(s * 2 + h) * 1024
                                               + (size_t)(g * 32 + l) * 16);
    }

    const int i00 = i0 + w2 * 64 + 4 * h;   // epilogue row base for this lane
    const int cb  = wc * 32 + l;            // col offset within tile
    const size_t lane_off = (size_t)cb * 16 + (size_t)h * 1024;

    // z0 tile k -> column origin
    auto c0z0 = [&](int k) -> int {
        int e = (k == 0) ? 64 : e1 + (k - 1) * 64;
        return (i0 + e) & BMASK;
    };

    float s0 = 0.f, s1 = 0.f, s2 = 0.f, s3 = 0.f;
    bf16x8 bE0, bE1, bE2, bE3, bE4, bE5, bE6, bE7;
    bf16x8 bO0, bO1, bO2, bO3, bO4, bO5, bO6, bO7;
    f32x16 aE0, aE1, aO0, aO1;

    if (z == 1) {
        // ---- z1: maskless pipeline; tile k block base = Bpack + k*BLK64 ----
        LOADB(E, Bpack + (size_t)k0 * BLK64 + lane_off);
        LOADB(O, Bpack + (size_t)(k0 + 1) * BLK64 + lane_off);
        BODY0(E, aE0, aE1,
              if (k0 + 2 < k1) LOADB(E, Bpack + (size_t)(k0 + 2) * BLK64 + lane_off));
        int k = k0 + 1;
        while (k + 1 < k1) {
            BODY_NM(O, aO0, aO1, aE0, aE1,
                    if (k + 2 < k1) LOADB(O, Bpack + (size_t)(k + 2) * BLK64 + lane_off));
            BODY_NM(E, aE0, aE1, aO0, aO1,
                    if (k + 3 < k1) LOADB(E, Bpack + (size_t)(k + 3) * BLK64 + lane_off));
            k += 2;
        }
        if (k < k1) {
            BODY_NM(O, aO0, aO1, aE0, aE1, ((void)0));
            s0 += tile_sum<false>(aO0, aO1, i00, 0);
        } else {
            s0 += tile_sum<false>(aE0, aE1, i00, 0);
        }
    } else {
        // ---- z0: always-masked pipeline ((d > i) is universally correct) ----
        int cE = c0z0(k0) + cb, cO = c0z0(k0 + 1) + cb;
        LOADB(E, Bpack + (size_t)(c0z0(k0) >> 6) * BLK64 + lane_off);
        LOADB(O, Bpack + (size_t)(c0z0(k0 + 1) >> 6) * BLK64 + lane_off);
        BODY0(E, aE0, aE1,
              if (k0 + 2 < k1) LOADB(E, Bpack + (size_t)(c0z0(k0 + 2) >> 6) * BLK64 + lane_off));
        int k = k0 + 1;
        while (k + 1 < k1) {
            BODY_M(O, aO0, aO1, aE0, aE1, cE,
                   if (k + 2 < k1) LOADB(O, Bpack + (size_t)(c0z0(k + 2) >> 6) * BLK64 + lane_off));
            cE = c0z0(k + 1) + cb;
            BODY_M(E, aE0, aE1, aO0, aO1, cO,
                   if (k + 3 < k1) LOADB(E, Bpack + (size_t)(c0z0(k + 3) >> 6) * BLK64 + lane_off));
            cO = c0z0(k + 2) + cb;   // valid only if tile k+2 exists; guarded by use
            k += 2;
        }
        if (k < k1) {
            BODY_M(O, aO0, aO1, aE0, aE1, cE, ((void)0));
            s0 += tile_sum<true>(aO0, aO1, i00, c0z0(k) + cb);
        } else {
            s0 += tile_sum<true>(aE0, aE1, i00, cE);
        }
    }

    float sacc = (s0 + s1) + (s2 + s3);
#pragma unroll
    for (int o = 32; o > 0; o >>= 1) sacc += __shfl_down(sacc, o);
    if (lane == 0) red[w] = sacc;
    __syncthreads();
    if (tid == 0) {
        atomicAdd(&accg[z], red[0] + red[1] + red[2] + red[3]);
        __threadfence();
        unsigned prev = atomicAdd((unsigned*)&accg[2], 1u);
        if (prev == (unsigned)(nblocks - 1)) {
            float l1 = atomicAdd(&accg[0], 0.f);
            float l2 = atomicAdd(&accg[1], 0.f);
            out[0] = -logf(l1 / l2);
        }
    }
}

extern "C" void kernel_launch(void* const* d_in, const int* in_sizes, int n_in,
                              void* d_out, int out_size, void* d_ws, size_t ws_size,
                              hipStream_t stream) {
    (void)in_sizes; (void)n_in; (void)out_size; (void)ws_size;
    const float* e1 = (const float*)d_in[0];
    const float* e2 = (const float*)d_in[1];
    float* out = (float*)d_out;
    char*  ws  = (char*)d_ws;

    float* acc = (float*)ws;                       // 16 B: l1, l2, counter, pad
    char*  p1  = ws + 4096;                        // 2 MB packed E1
    char*  p2  = ws + 4096 + 2097152;              // 2 MB packed E2

    // z0 block count (must match device-side mapping; z1 blocks come first)
    int nz0 = 0;
    for (int p = 0; p < 64; ++p) {
        int i0 = 128 * p;
        int e1t = (i0 > 128) ? i0 : 128;
        int cnt = 2 + (B_ROWS - e1t) / 64;
        nz0 += (cnt + CHUNK0 - 1) / CHUNK0;
    }
    int nblocks = NZ1 + nz0;   // 256 + 244 = 500 <= 512 (2 blocks/CU) -> one round

    prep_kernel<<<dim3(4096), dim3(256), 0, stream>>>(e1, e2, p1, p2, acc);
    pair_kernel<<<dim3(nblocks), dim3(256), 0, stream>>>(p1, p2, acc, out, nblocks);
}